// Round 4
// baseline (98.662 us; speedup 1.0000x reference)
//
#include <hip/hip_runtime.h>

// B=8, N=256, M=16, D=256
// loss = sum_rows logsumexp_k(S) - sum S_self, S = w*<e,c_k>+b, LOO diagonal
constexpr int B = 8, N = 256, M = 16, D = 256;

typedef short bf16x8 __attribute__((ext_vector_type(8)));
typedef float f32x4 __attribute__((ext_vector_type(4)));

__device__ __forceinline__ unsigned short f2bf(float x) {
  unsigned u = __float_as_uint(x);
  u = (u + 0x7FFFu + ((u >> 16) & 1u)) >> 16;  // RNE
  return (unsigned short)u;
}
__device__ __forceinline__ uint4 packbf8(const float* f) {
  uint4 u;
  u.x = (unsigned)f2bf(f[0]) | ((unsigned)f2bf(f[1]) << 16);
  u.y = (unsigned)f2bf(f[2]) | ((unsigned)f2bf(f[3]) << 16);
  u.z = (unsigned)f2bf(f[4]) | ((unsigned)f2bf(f[5]) << 16);
  u.w = (unsigned)f2bf(f[6]) | ((unsigned)f2bf(f[7]) << 16);
  return u;
}

// ws: Cbf [0,1MB) B-frags: uint4[(b*8+kc)*16+nt][lane]; lane l holds
//     col n=nt*16+(l&15), dims kc*32+(l>>4)*8..+7 of centroid matrix.

// Centroid-only prep: one block per (b,j); thread t = dim d.
__global__ __launch_bounds__(256) void k_prep(const float* __restrict__ e,
                                              uint4* __restrict__ Cbf,
                                              float* __restrict__ out) {
  const int blk = blockIdx.x;  // b*256 + j
  const int b = blk >> 8, j = blk & 255;
  const int t = threadIdx.x;
  const float* base = e + (size_t)blk * (M * D);
  float s = 0.f;
#pragma unroll
  for (int i = 0; i < M; ++i) s += base[i * D + t];  // coalesced 1KB per iter
  __shared__ float cl[D];
  cl[t] = s * (1.f / 16.f);
  __syncthreads();
  if (t < 32) {
    const int kc = t >> 2, qq = t & 3;
    float f[8];
#pragma unroll
    for (int x = 0; x < 8; ++x) f[x] = cl[kc * 32 + qq * 8 + x];
    Cbf[(size_t)((b * 8 + kc) * 16 + (j >> 4)) * 64 + qq * 16 + (j & 15)] = packbf8(f);
  }
  if (blk == 0 && t == 0) out[0] = 0.f;  // d_out re-poisoned each launch
}

// One block per (b, 64-row strip). 4 waves 2x2: h=row-half (2 tiles), c=col-half (8 nt).
// A-frags loaded DIRECTLY from fp32 E (8 contiguous floats/lane), converted in-register.
// sqnorm computed inline in the k-loop (fp32 exact).
__global__ __launch_bounds__(256) void k_gemm(const float* __restrict__ e,
                                              const uint4* __restrict__ Cbf,
                                              const float* __restrict__ wp,
                                              const float* __restrict__ bp,
                                              float* __restrict__ out) {
  const int blk = blockIdx.x;  // b*64 + strip
  const int b = blk >> 6, strip = blk & 63;
  const int tid = threadIdx.x;
  const int wid = tid >> 6, lane = tid & 63;
  const int h = wid >> 1, c = wid & 1;
  const int q = lane >> 4, m = lane & 15;

  // lane's A source: row R = (strip*4 + h*2 + rt)*16 + m, dims kc*32 + q*8 ..
  const float* Abase =
      e + (size_t)b * (N * M * D) + (size_t)((strip * 4 + h * 2) * 16 + m) * D + q * 8;
  const uint4* Bb = Cbf + (size_t)(b * 128 + c * 8) * 64 + lane;

  f32x4 acc[2][8];
#pragma unroll
  for (int rt = 0; rt < 2; ++rt)
#pragma unroll
    for (int nt = 0; nt < 8; ++nt) acc[rt][nt] = (f32x4)0.f;
  float sqp[2] = {0.f, 0.f};

#pragma unroll 1
  for (int kc = 0; kc < 8; ++kc) {
    float fa[2][8];
#pragma unroll
    for (int rt = 0; rt < 2; ++rt) {
      const float4 lo = *(const float4*)(Abase + (size_t)rt * 16 * D + kc * 32);
      const float4 hi = *(const float4*)(Abase + (size_t)rt * 16 * D + kc * 32 + 4);
      fa[rt][0] = lo.x; fa[rt][1] = lo.y; fa[rt][2] = lo.z; fa[rt][3] = lo.w;
      fa[rt][4] = hi.x; fa[rt][5] = hi.y; fa[rt][6] = hi.z; fa[rt][7] = hi.w;
#pragma unroll
      for (int x = 0; x < 8; ++x) sqp[rt] = fmaf(fa[rt][x], fa[rt][x], sqp[rt]);
    }
    uint4 a0 = packbf8(fa[0]);
    uint4 a1 = packbf8(fa[1]);
    uint4 bfr[8];
#pragma unroll
    for (int nt = 0; nt < 8; ++nt) bfr[nt] = Bb[(kc * 16 + nt) * 64];
    bf16x8 av0 = __builtin_bit_cast(bf16x8, a0);
    bf16x8 av1 = __builtin_bit_cast(bf16x8, a1);
#pragma unroll
    for (int nt = 0; nt < 8; ++nt) {
      bf16x8 bv = __builtin_bit_cast(bf16x8, bfr[nt]);
      acc[0][nt] = __builtin_amdgcn_mfma_f32_16x16x32_bf16(av0, bv, acc[0][nt], 0, 0, 0);
      acc[1][nt] = __builtin_amdgcn_mfma_f32_16x16x32_bf16(av1, bv, acc[1][nt], 0, 0, 0);
    }
  }

  // sqnorm: reduce over q lane bits -> every lane holds full ||row m||^2
#pragma unroll
  for (int rt = 0; rt < 2; ++rt) {
    sqp[rt] += __shfl_xor(sqp[rt], 16, 64);
    sqp[rt] += __shfl_xor(sqp[rt], 32, 64);
  }
  // move to C-layout rows: lane needs rows q*4+reg (source lane q*4+reg holds row m=q*4+reg)
  float sqv[2][4];
#pragma unroll
  for (int rt = 0; rt < 2; ++rt)
#pragma unroll
    for (int reg = 0; reg < 4; ++reg) sqv[rt][reg] = __shfl(sqp[rt], q * 4 + reg, 64);

  // ---- epilogue: scale, LOO diagonal, logsumexp ----
  const float w = *wp, bias = *bp;
  __shared__ float lmx[2][64];
  __shared__ float lsm[2][64];
  __shared__ float bred[4];
  float ssum = 0.f;

#pragma unroll
  for (int rt = 0; rt < 2; ++rt) {
    const int jr = strip * 4 + h * 2 + rt;  // global row-tile == diag col
    const bool own = (c == (jr >> 7)) && (m == (jr & 15));
    const int ntd = (jr >> 4) & 7;
#pragma unroll
    for (int nt = 0; nt < 8; ++nt)
#pragma unroll
      for (int reg = 0; reg < 4; ++reg) {
        const float raw = acc[rt][nt][reg];
        float sv = fmaf(w, raw, bias);
        if (own && nt == ntd) {  // predicated, no dynamic reg indexing
          sv = fmaf(w * (1.f / 15.f), 16.f * raw - sqv[rt][reg], bias);
          ssum += sv;
        }
        acc[rt][nt][reg] = sv;
      }
#pragma unroll
    for (int reg = 0; reg < 4; ++reg) {
      float mx = acc[rt][0][reg];
#pragma unroll
      for (int nt = 1; nt < 8; ++nt) mx = fmaxf(mx, acc[rt][nt][reg]);
#pragma unroll
      for (int mk = 1; mk < 16; mk <<= 1) mx = fmaxf(mx, __shfl_xor(mx, mk, 64));
      if (m == 0) lmx[c][(h * 2 + rt) * 16 + q * 4 + reg] = mx;
    }
  }
  __syncthreads();

#pragma unroll
  for (int rt = 0; rt < 2; ++rt)
#pragma unroll
    for (int reg = 0; reg < 4; ++reg) {
      const int Rl = (h * 2 + rt) * 16 + q * 4 + reg;
      const float mx = fmaxf(lmx[0][Rl], lmx[1][Rl]);
      float se = 0.f;
#pragma unroll
      for (int nt = 0; nt < 8; ++nt) se += __expf(acc[rt][nt][reg] - mx);
#pragma unroll
      for (int mk = 1; mk < 16; mk <<= 1) se += __shfl_xor(se, mk, 64);
      if (m == 0) lsm[c][Rl] = se;
    }
  __syncthreads();

  float part = -ssum;
  if (c == 0 && m == 0) {
#pragma unroll
    for (int rt = 0; rt < 2; ++rt)
#pragma unroll
      for (int reg = 0; reg < 4; ++reg) {
        const int Rl = (h * 2 + rt) * 16 + q * 4 + reg;
        const float mx = fmaxf(lmx[0][Rl], lmx[1][Rl]);
        part += mx + __logf(lsm[0][Rl] + lsm[1][Rl]);
      }
  }
#pragma unroll
  for (int mk = 1; mk < 64; mk <<= 1) part += __shfl_xor(part, mk, 64);
  if (lane == 0) bred[wid] = part;
  __syncthreads();
  if (tid == 0) atomicAdd(out, bred[0] + bred[1] + bred[2] + bred[3]);
}

extern "C" void kernel_launch(void* const* d_in, const int* in_sizes, int n_in,
                              void* d_out, int out_size, void* d_ws, size_t ws_size,
                              hipStream_t stream) {
  const float* e = (const float*)d_in[0];
  const float* wp = (const float*)d_in[1];
  const float* bp = (const float*)d_in[2];
  float* out = (float*)d_out;
  uint4* Cbf = (uint4*)d_ws;  // 1 MB B-fragment centroids

  k_prep<<<B * N, 256, 0, stream>>>(e, Cbf, out);
  k_gemm<<<B * 64, 256, 0, stream>>>(e, Cbf, wp, bp, out);
}